// Round 1
// baseline (514.834 us; speedup 1.0000x reference)
//
#include <hip/hip_runtime.h>
#include <math.h>

#define LOG2PI_F 0.9189385332046727f

// ---------------------------------------------------------------------------
// Kernel 1: softmax over k of every w[f][j][k], all 8 levels concatenated,
// stored TRANSPOSED: wpT[g][k][j] = softmax(w_g, axis=k)[j][k].
// g-slot bases: lvl1:0 lvl2:128 lvl3:192 lvl4:224 lvl5:240 lvl6:248 lvl7:252 lvl8:254
// ---------------------------------------------------------------------------
__global__ __launch_bounds__(256) void softmax_kernel(
    const float* __restrict__ w1, const float* __restrict__ w2,
    const float* __restrict__ w3, const float* __restrict__ w4,
    const float* __restrict__ w5, const float* __restrict__ w6,
    const float* __restrict__ w7, const float* __restrict__ w8,
    float* __restrict__ wpT)
{
    __shared__ float smax[64], ssum[64];
    const int g = blockIdx.x;
    const float* src;
    if (g < 128)      src = w1 + (g      ) * 4096;
    else if (g < 192) src = w2 + (g - 128) * 4096;
    else if (g < 224) src = w3 + (g - 192) * 4096;
    else if (g < 240) src = w4 + (g - 224) * 4096;
    else if (g < 248) src = w5 + (g - 240) * 4096;
    else if (g < 252) src = w6 + (g - 248) * 4096;
    else if (g < 254) src = w7 + (g - 252) * 4096;
    else              src = w8;

    const int t = threadIdx.x;
    const int lane = t & 63, wv = t >> 6;
    for (int r = 0; r < 16; ++r) {
        int j = wv * 16 + r;
        float v = src[j * 64 + lane];
        float mx = v;
        for (int d = 1; d < 64; d <<= 1) mx = fmaxf(mx, __shfl_xor(mx, d, 64));
        float e = __expf(v - mx);
        float s = e;
        for (int d = 1; d < 64; d <<= 1) s += __shfl_xor(s, d, 64);
        if (lane == 0) { smax[j] = mx; ssum[j] = s; }
    }
    __syncthreads();
    float* dst = wpT + g * 4096;
    for (int u = 0; u < 16; ++u) {
        int idx = u * 256 + t;
        int k = idx >> 6, j = idx & 63;
        dst[idx] = __expf(src[j * 64 + k] - smax[j]) / ssum[j];
    }
}

// ---------------------------------------------------------------------------
// Generic fused subtree kernel. Post-order DFS over a complete binary tree of
// `nl` local levels rooted at node s (= blockIdx.x % nsub). Value stack of
// K=64 vectors for a 32-row batch tile lives in LDS (5 slots, stride 68 to
// break bank conflicts). Per node:
//   h = c0 + c1 (regs); m = rowmax (shuffles); p = exp(h-m) -> LDS;
//   out[b][j] = log( sum_k p[b][k] * wp[j][k] ) + m[b]   (block matmul)
// GAUSS=true: level-1 children are Gaussian leaves (d indices).
// GAUSS=false: level-1 children are precomputed node vectors in in5[8][2048][64].
// ---------------------------------------------------------------------------
struct Op { int w; int c0; int c1; int leaf; };

template<bool GAUSS>
__global__ __launch_bounds__(256) void circuit_kernel(
    const float* __restrict__ wpT,
    const int* __restrict__ fA, int nA,
    const int* __restrict__ fB, int nB,
    const int* __restrict__ fC, int nC,
    const int* __restrict__ fD, int nD,
    const int* __restrict__ fE, int nE,
    int nl,
    int wb1, int wb2, int wb3, int wb4, int wb5,
    int nsub,
    const float* __restrict__ x, const float* __restrict__ mu,
    const float* __restrict__ ls, const int* __restrict__ scope,
    const float* __restrict__ in5,
    float* __restrict__ outg)
{
    __shared__ float slot[5][32 * 68];   // value stack: 43.5 KB
    __shared__ float wbuf[4096];         // staged wp (k-major): 16 KB
    __shared__ float mbuf[32];
    __shared__ Op    ops[31];
    __shared__ int   sfold[512];
    __shared__ int   snops;

    const int t  = threadIdx.x;
    const int s  = blockIdx.x % nsub;
    const int b0 = (blockIdx.x / nsub) * 32;

    // ---- stage fold index arrays into LDS (cheap schedule gen afterwards)
    const int o1 = 0, o2 = 2 * nA, o3 = o2 + 2 * nB, o4 = o3 + 2 * nC, o5 = o4 + 2 * nD;
    for (int i = t; i < 2 * nA; i += 256) sfold[o1 + i] = fA[i];
    for (int i = t; i < 2 * nB; i += 256) sfold[o2 + i] = fB[i];
    for (int i = t; i < 2 * nC; i += 256) sfold[o3 + i] = fC[i];
    for (int i = t; i < 2 * nD; i += 256) sfold[o4 + i] = fD[i];
    for (int i = t; i < 2 * nE; i += 256) sfold[o5 + i] = fE[i];
    __syncthreads();

    // ---- post-order schedule (thread 0, all in LDS/regs)
    if (t == 0) {
        int ofs[6]; ofs[1] = o1; ofs[2] = o2; ofs[3] = o3; ofs[4] = o4; ofs[5] = o5;
        int wb[6];  wb[1] = wb1; wb[2] = wb2; wb[3] = wb3; wb[4] = wb4; wb[5] = wb5;
        int sl[8], sf[8], st[8]; int sp = 0;
        sl[0] = nl; sf[0] = s; st[0] = 0; sp = 1;
        int n = 0;
        while (sp > 0) {
            int l = sl[sp - 1], f = sf[sp - 1];
            if (l == 1) {
                ops[n].w = (wb[1] + f) * 4096;
                ops[n].c0 = sfold[ofs[1] + 2 * f];
                ops[n].c1 = sfold[ofs[1] + 2 * f + 1];
                ops[n].leaf = 1; n++; sp--;
            } else if (st[sp - 1] == 0) {
                st[sp - 1] = 1;
                sl[sp] = l - 1; sf[sp] = sfold[ofs[l] + 2 * f]; st[sp] = 0; sp++;
            } else if (st[sp - 1] == 1) {
                st[sp - 1] = 2;
                sl[sp] = l - 1; sf[sp] = sfold[ofs[l] + 2 * f + 1]; st[sp] = 0; sp++;
            } else {
                ops[n].w = (wb[l] + f) * 4096;
                ops[n].c0 = 0; ops[n].c1 = 0; ops[n].leaf = 0; n++; sp--;
            }
        }
        snops = n;
    }
    __syncthreads();
    const int nops = snops;

    const int wv = t >> 6;          // wave 0..3
    const int j  = t & 63;          // output column lane
    const int rb = t >> 3;          // elementwise row 0..31
    const int kc = t & 7;           // elementwise k-chunk
    const int k0 = kc * 8;
    const int w8 = wv * 8;          // this wave's first row in matmul phase

    int vsp = 0;
    for (int io = 0; io < nops; ++io) {
        const Op op = ops[io];
        int curO, curP;
        if (op.leaf) { curO = vsp; curP = vsp; vsp++; }   // p in-place over push slot
        else         { curO = vsp - 2; curP = vsp - 1; vsp--; }

        // stage wp[f] (transposed [k][j]) into LDS
        {
            const float4* src4 = (const float4*)(wpT + op.w);
            float4* dst4 = (float4*)wbuf;
            #pragma unroll
            for (int u = 0; u < 4; ++u) dst4[u * 256 + t] = src4[u * 256 + t];
        }

        // ---- elementwise: h (regs) -> rowmax -> p (LDS)
        float h[8];
        if (op.leaf) {
            if (GAUSS) {
                const int d0 = op.c0, d1 = op.c1;
                const int v0 = scope[d0], v1 = scope[d1];
                const float* mu0 = mu + d0 * 64 + k0;
                const float* ls0 = ls + d0 * 64 + k0;
                const float* mu1 = mu + d1 * 64 + k0;
                const float* ls1 = ls + d1 * 64 + k0;
                const float xv0 = x[(b0 + rb) * 256 + v0];
                const float xv1 = x[(b0 + rb) * 256 + v1];
                #pragma unroll
                for (int i = 0; i < 8; ++i) {
                    float l0v = ls0[i], l1v = ls1[i];
                    float z0 = (xv0 - mu0[i]) * __expf(-l0v);
                    float z1 = (xv1 - mu1[i]) * __expf(-l1v);
                    h[i] = (-0.5f * z0 * z0 - l0v - LOG2PI_F)
                         + (-0.5f * z1 * z1 - l1v - LOG2PI_F);
                }
            } else {
                const float* p0 = in5 + (op.c0 * 2048 + b0 + rb) * 64 + k0;
                const float* p1 = in5 + (op.c1 * 2048 + b0 + rb) * 64 + k0;
                #pragma unroll
                for (int i = 0; i < 8; ++i) h[i] = p0[i] + p1[i];
            }
        } else {
            const float* A = &slot[curO][rb * 68 + k0];
            const float* B = &slot[curP][rb * 68 + k0];
            #pragma unroll
            for (int i = 0; i < 8; ++i) h[i] = A[i] + B[i];
        }
        float hm = h[0];
        #pragma unroll
        for (int i = 1; i < 8; ++i) hm = fmaxf(hm, h[i]);
        hm = fmaxf(hm, __shfl_xor(hm, 1, 64));
        hm = fmaxf(hm, __shfl_xor(hm, 2, 64));
        hm = fmaxf(hm, __shfl_xor(hm, 4, 64));
        if (kc == 0) mbuf[rb] = hm;
        {
            float* P = &slot[curP][rb * 68 + k0];
            #pragma unroll
            for (int i = 0; i < 8; ++i) P[i] = __expf(h[i] - hm);
        }
        __syncthreads();   // wbuf staged + p/m visible

        // ---- matmul: out[b][j] = log( sum_k p[b][k] * wbuf[k][j] ) + m[b]
        float acc[8];
        #pragma unroll
        for (int bb = 0; bb < 8; ++bb) acc[bb] = 0.f;
        #pragma unroll
        for (int k = 0; k < 64; k += 4) {
            const float w0 = wbuf[(k + 0) * 64 + j];
            const float w1 = wbuf[(k + 1) * 64 + j];
            const float w2 = wbuf[(k + 2) * 64 + j];
            const float w3 = wbuf[(k + 3) * 64 + j];
            #pragma unroll
            for (int bb = 0; bb < 8; ++bb) {
                const float4 p4 = *(const float4*)&slot[curP][(w8 + bb) * 68 + k];
                acc[bb] = fmaf(p4.x, w0, acc[bb]);
                acc[bb] = fmaf(p4.y, w1, acc[bb]);
                acc[bb] = fmaf(p4.z, w2, acc[bb]);
                acc[bb] = fmaf(p4.w, w3, acc[bb]);
            }
        }
        const bool root = (io == nops - 1);
        #pragma unroll
        for (int bb = 0; bb < 8; ++bb) {
            float v = __logf(acc[bb]) + mbuf[w8 + bb];
            if (root) {
                int b = b0 + w8 + bb;
                if (GAUSS) outg[(s * 2048 + b) * 64 + j] = v;
                else       outg[b * 64 + j] = v;
            } else {
                slot[curO][(w8 + bb) * 68 + j] = v;
            }
        }
        __syncthreads();   // protect wbuf/slots before next op
    }
}

// ---------------------------------------------------------------------------
// d_in order (setup_inputs dict order):
// 0:x 1:mu 2:log_sigma 3:in_scope_idx, then fold_idx{l}, w{l} for l=1..8
// ---------------------------------------------------------------------------
extern "C" void kernel_launch(void* const* d_in, const int* in_sizes, int n_in,
                              void* d_out, int out_size, void* d_ws, size_t ws_size,
                              hipStream_t stream) {
    const float* x     = (const float*)d_in[0];
    const float* mu    = (const float*)d_in[1];
    const float* lsg   = (const float*)d_in[2];
    const int*   scope = (const int*)d_in[3];
    const int*   f1 = (const int*)d_in[4];   const float* w1 = (const float*)d_in[5];
    const int*   f2 = (const int*)d_in[6];   const float* w2 = (const float*)d_in[7];
    const int*   f3 = (const int*)d_in[8];   const float* w3 = (const float*)d_in[9];
    const int*   f4 = (const int*)d_in[10];  const float* w4 = (const float*)d_in[11];
    const int*   f5 = (const int*)d_in[12];  const float* w5 = (const float*)d_in[13];
    const int*   f6 = (const int*)d_in[14];  const float* w6 = (const float*)d_in[15];
    const int*   f7 = (const int*)d_in[16];  const float* w7 = (const float*)d_in[17];
    const int*   f8 = (const int*)d_in[18];  const float* w8 = (const float*)d_in[19];

    float* wpT  = (float*)d_ws;               // 255*4096 floats = 4.18 MB
    float* out5 = wpT + 255 * 4096;           // 8*2048*64 floats = 4.19 MB

    // 1) softmax all mixture weights (transposed for conflict-free LDS reads)
    softmax_kernel<<<255, 256, 0, stream>>>(w1, w2, w3, w4, w5, w6, w7, w8, wpT);

    // 2) levels 1..5: 8 subtrees x 64 batch tiles of 32
    circuit_kernel<true><<<512, 256, 0, stream>>>(
        wpT,
        f1, 128, f2, 64, f3, 32, f4, 16, f5, 8,
        5,
        0, 128, 192, 224, 240,
        8,
        x, mu, lsg, scope,
        nullptr,
        out5);

    // 3) levels 6..8: single tree over the 8 level-5 nodes, 64 batch tiles
    circuit_kernel<false><<<64, 256, 0, stream>>>(
        wpT,
        f6, 4, f7, 2, f8, 1, f8, 0, f8, 0,
        3,
        248, 252, 254, 0, 0,
        1,
        nullptr, nullptr, nullptr, nullptr,
        out5,
        (float*)d_out);
}

// Round 2
// 348.478 us; speedup vs baseline: 1.4774x; 1.4774x over previous
//
#include <hip/hip_runtime.h>
#include <hip/hip_bf16.h>
#include <math.h>

#define LOG2PI_F 0.9189385332046727f

// ---------------------------------------------------------------------------
// Kernel 1: softmax over k of every w[f][j][k], all 8 levels concatenated,
// emitted as bf16, j-major (same orientation as source): wbJ[g][j][k].
// g-slot bases: lvl1:0 lvl2:128 lvl3:192 lvl4:224 lvl5:240 lvl6:248 lvl7:252 lvl8:254
// ---------------------------------------------------------------------------
__global__ __launch_bounds__(256) void softmax_kernel(
    const float* __restrict__ w1, const float* __restrict__ w2,
    const float* __restrict__ w3, const float* __restrict__ w4,
    const float* __restrict__ w5, const float* __restrict__ w6,
    const float* __restrict__ w7, const float* __restrict__ w8,
    __hip_bfloat16* __restrict__ wbJ)
{
    __shared__ float smax[64], ssum[64];
    const int g = blockIdx.x;
    const float* src;
    if (g < 128)      src = w1 + (g      ) * 4096;
    else if (g < 192) src = w2 + (g - 128) * 4096;
    else if (g < 224) src = w3 + (g - 192) * 4096;
    else if (g < 240) src = w4 + (g - 224) * 4096;
    else if (g < 248) src = w5 + (g - 240) * 4096;
    else if (g < 252) src = w6 + (g - 248) * 4096;
    else              src = (g < 254) ? (w7 + (g - 252) * 4096) : w8;

    const int t = threadIdx.x;
    const int lane = t & 63, wv = t >> 6;
    for (int r = 0; r < 16; ++r) {
        int j = wv * 16 + r;
        float v = src[j * 64 + lane];
        float mx = v;
        for (int d = 1; d < 64; d <<= 1) mx = fmaxf(mx, __shfl_xor(mx, d, 64));
        float e = __expf(v - mx);
        float s = e;
        for (int d = 1; d < 64; d <<= 1) s += __shfl_xor(s, d, 64);
        if (lane == 0) { smax[j] = mx; ssum[j] = s; }
    }
    __syncthreads();
    __hip_bfloat16* dst = wbJ + g * 4096;
    for (int u = 0; u < 16; ++u) {
        int idx = u * 256 + t;
        int j = idx >> 6;
        dst[idx] = __float2bfloat16(__expf(src[idx] - smax[j]) / ssum[j]);
    }
}

// ---------------------------------------------------------------------------
// Fused subtree kernel, BARRIER-FREE op loop.
// Block = 256 threads = 4 waves; each wave owns 4 batch rows of a 16-row tile
// and walks the post-order schedule independently (all inter-op dependencies
// are intra-wave: wave w writes exactly the rows it later reads). Weights are
// read directly from global bf16 (L2-resident, 2.1 MB total) — no LDS staging,
// so no __syncthreads after schedule generation.
// ---------------------------------------------------------------------------
struct Op { int w; int c0; int c1; int leaf; };

__device__ __forceinline__ float bf2f(unsigned short u) {
    return __uint_as_float(((unsigned int)u) << 16);
}

template<bool GAUSS>
__global__ __launch_bounds__(256, 4) void circuit_kernel(
    const unsigned short* __restrict__ wbJ,
    const int* __restrict__ fA, int nA,
    const int* __restrict__ fB, int nB,
    const int* __restrict__ fC, int nC,
    const int* __restrict__ fD, int nD,
    const int* __restrict__ fE, int nE,
    int nl,
    int wb1, int wb2, int wb3, int wb4, int wb5,
    int nsub,
    const float* __restrict__ x, const float* __restrict__ mu,
    const float* __restrict__ ls, const int* __restrict__ scope,
    const float* __restrict__ in5,
    float* __restrict__ outg)
{
    __shared__ float slot[5][16 * 68];   // value stack: 21.25 KB
    __shared__ float mbuf[16];
    __shared__ Op    ops[31];
    __shared__ int   sfold[512];
    __shared__ int   snops;

    const int t  = threadIdx.x;
    const int s  = blockIdx.x % nsub;
    const int b0 = (blockIdx.x / nsub) * 16;

    // ---- stage fold index arrays into LDS
    const int o1 = 0, o2 = 2 * nA, o3 = o2 + 2 * nB, o4 = o3 + 2 * nC, o5 = o4 + 2 * nD;
    for (int i = t; i < 2 * nA; i += 256) sfold[o1 + i] = fA[i];
    for (int i = t; i < 2 * nB; i += 256) sfold[o2 + i] = fB[i];
    for (int i = t; i < 2 * nC; i += 256) sfold[o3 + i] = fC[i];
    for (int i = t; i < 2 * nD; i += 256) sfold[o4 + i] = fD[i];
    for (int i = t; i < 2 * nE; i += 256) sfold[o5 + i] = fE[i];
    __syncthreads();

    // ---- post-order schedule (thread 0)
    if (t == 0) {
        int ofs[6]; ofs[1] = o1; ofs[2] = o2; ofs[3] = o3; ofs[4] = o4; ofs[5] = o5;
        int wb[6];  wb[1] = wb1; wb[2] = wb2; wb[3] = wb3; wb[4] = wb4; wb[5] = wb5;
        int sl[8], sf[8], st[8]; int sp = 0;
        sl[0] = nl; sf[0] = s; st[0] = 0; sp = 1;
        int n = 0;
        while (sp > 0) {
            int l = sl[sp - 1], f = sf[sp - 1];
            if (l == 1) {
                ops[n].w = (wb[1] + f) * 4096;
                ops[n].c0 = sfold[ofs[1] + 2 * f];
                ops[n].c1 = sfold[ofs[1] + 2 * f + 1];
                ops[n].leaf = 1; n++; sp--;
            } else if (st[sp - 1] == 0) {
                st[sp - 1] = 1;
                sl[sp] = l - 1; sf[sp] = sfold[ofs[l] + 2 * f]; st[sp] = 0; sp++;
            } else if (st[sp - 1] == 1) {
                st[sp - 1] = 2;
                sl[sp] = l - 1; sf[sp] = sfold[ofs[l] + 2 * f + 1]; st[sp] = 0; sp++;
            } else {
                ops[n].w = (wb[l] + f) * 4096;
                ops[n].c0 = 0; ops[n].c1 = 0; ops[n].leaf = 0; n++; sp--;
            }
        }
        snops = n;
    }
    __syncthreads();            // the ONLY block-wide barrier
    const int nops = snops;

    const int wv = t >> 6;      // wave 0..3
    const int j  = t & 63;      // output column lane
    const int rb = t >> 4;      // elementwise row 0..15  (wave wv -> rows 4wv..4wv+3)
    const int kc = t & 15;      // elementwise k-chunk (4 wide)
    const int k0 = kc * 4;
    const int r0 = wv * 4;      // this wave's first row in matmul phase

    int vsp = 0;
    for (int io = 0; io < nops; ++io) {
        const Op op = ops[io];
        int curO, curP;
        if (op.leaf) { curO = vsp; curP = vsp; vsp++; }   // p in-place over push slot
        else         { curO = vsp - 2; curP = vsp - 1; vsp--; }

        // ---- elementwise: h (regs) -> rowmax -> p (LDS, own rows only)
        float h[4];
        if (op.leaf) {
            if (GAUSS) {
                const int d0 = op.c0, d1 = op.c1;
                const int v0 = scope[d0], v1 = scope[d1];
                const float4 mu0 = *(const float4*)(mu + d0 * 64 + k0);
                const float4 ls0 = *(const float4*)(ls + d0 * 64 + k0);
                const float4 mu1 = *(const float4*)(mu + d1 * 64 + k0);
                const float4 ls1 = *(const float4*)(ls + d1 * 64 + k0);
                const float xv0 = x[(b0 + rb) * 256 + v0];
                const float xv1 = x[(b0 + rb) * 256 + v1];
                const float m0[4] = {mu0.x, mu0.y, mu0.z, mu0.w};
                const float l0[4] = {ls0.x, ls0.y, ls0.z, ls0.w};
                const float m1[4] = {mu1.x, mu1.y, mu1.z, mu1.w};
                const float l1[4] = {ls1.x, ls1.y, ls1.z, ls1.w};
                #pragma unroll
                for (int i = 0; i < 4; ++i) {
                    float z0 = (xv0 - m0[i]) * __expf(-l0[i]);
                    float z1 = (xv1 - m1[i]) * __expf(-l1[i]);
                    h[i] = (-0.5f * z0 * z0 - l0[i] - LOG2PI_F)
                         + (-0.5f * z1 * z1 - l1[i] - LOG2PI_F);
                }
            } else {
                const float4 p0 = *(const float4*)(in5 + (op.c0 * 2048 + b0 + rb) * 64 + k0);
                const float4 p1 = *(const float4*)(in5 + (op.c1 * 2048 + b0 + rb) * 64 + k0);
                h[0] = p0.x + p1.x; h[1] = p0.y + p1.y;
                h[2] = p0.z + p1.z; h[3] = p0.w + p1.w;
            }
        } else {
            const float4 A = *(const float4*)&slot[curO][rb * 68 + k0];
            const float4 B = *(const float4*)&slot[curP][rb * 68 + k0];
            h[0] = A.x + B.x; h[1] = A.y + B.y;
            h[2] = A.z + B.z; h[3] = A.w + B.w;
        }
        float hm = fmaxf(fmaxf(h[0], h[1]), fmaxf(h[2], h[3]));
        hm = fmaxf(hm, __shfl_xor(hm, 1, 64));   // reduce over the 16 kc-lanes
        hm = fmaxf(hm, __shfl_xor(hm, 2, 64));   // sharing this row
        hm = fmaxf(hm, __shfl_xor(hm, 4, 64));
        hm = fmaxf(hm, __shfl_xor(hm, 8, 64));
        if (kc == 0) mbuf[rb] = hm;
        {
            float4 pv;
            pv.x = __expf(h[0] - hm); pv.y = __expf(h[1] - hm);
            pv.z = __expf(h[2] - hm); pv.w = __expf(h[3] - hm);
            *(float4*)&slot[curP][rb * 68 + k0] = pv;
        }
        __builtin_amdgcn_wave_barrier();   // compiler fence: p/m writes before reads

        // ---- matmul: out[b][j] = log( sum_k p[b][k] * wp[j][k] ) + m[b]
        // weights straight from global bf16 (L2-resident), p via LDS broadcast
        float acc[4] = {0.f, 0.f, 0.f, 0.f};
        const unsigned short* wrow = wbJ + op.w + j * 64;
        #pragma unroll
        for (int k = 0; k < 64; k += 4) {
            const ushort4 wu = *(const ushort4*)(wrow + k);
            const float w0 = bf2f(wu.x), w1 = bf2f(wu.y);
            const float w2 = bf2f(wu.z), w3 = bf2f(wu.w);
            #pragma unroll
            for (int r = 0; r < 4; ++r) {
                const float4 p4 = *(const float4*)&slot[curP][(r0 + r) * 68 + k];
                acc[r] = fmaf(p4.x, w0, acc[r]);
                acc[r] = fmaf(p4.y, w1, acc[r]);
                acc[r] = fmaf(p4.z, w2, acc[r]);
                acc[r] = fmaf(p4.w, w3, acc[r]);
            }
        }
        const bool root = (io == nops - 1);
        #pragma unroll
        for (int r = 0; r < 4; ++r) {
            float v = __logf(acc[r]) + mbuf[r0 + r];
            if (root) {
                int b = b0 + r0 + r;
                if (GAUSS) outg[(s * 2048 + b) * 64 + j] = v;
                else       outg[b * 64 + j] = v;
            } else {
                slot[curO][(r0 + r) * 68 + j] = v;
            }
        }
        __builtin_amdgcn_wave_barrier();   // compiler fence: out writes before next op
    }
}

// ---------------------------------------------------------------------------
// d_in order (setup_inputs dict order):
// 0:x 1:mu 2:log_sigma 3:in_scope_idx, then fold_idx{l}, w{l} for l=1..8
// ---------------------------------------------------------------------------
extern "C" void kernel_launch(void* const* d_in, const int* in_sizes, int n_in,
                              void* d_out, int out_size, void* d_ws, size_t ws_size,
                              hipStream_t stream) {
    const float* x     = (const float*)d_in[0];
    const float* mu    = (const float*)d_in[1];
    const float* lsg   = (const float*)d_in[2];
    const int*   scope = (const int*)d_in[3];
    const int*   f1 = (const int*)d_in[4];   const float* w1 = (const float*)d_in[5];
    const int*   f2 = (const int*)d_in[6];   const float* w2 = (const float*)d_in[7];
    const int*   f3 = (const int*)d_in[8];   const float* w3 = (const float*)d_in[9];
    const int*   f4 = (const int*)d_in[10];  const float* w4 = (const float*)d_in[11];
    const int*   f5 = (const int*)d_in[12];  const float* w5 = (const float*)d_in[13];
    const int*   f6 = (const int*)d_in[14];  const float* w6 = (const float*)d_in[15];
    const int*   f7 = (const int*)d_in[16];  const float* w7 = (const float*)d_in[17];
    const int*   f8 = (const int*)d_in[18];  const float* w8 = (const float*)d_in[19];

    __hip_bfloat16* wbJ = (__hip_bfloat16*)d_ws;        // 255*4096*2 B = 2.09 MB
    float* out5 = (float*)((char*)d_ws + (4 << 20));    // 8*2048*64*4 B = 4.19 MB

    // 1) softmax all mixture weights -> bf16, j-major
    softmax_kernel<<<255, 256, 0, stream>>>(w1, w2, w3, w4, w5, w6, w7, w8, wbJ);

    // 2) levels 1..5: 8 subtrees x 128 batch tiles of 16
    circuit_kernel<true><<<1024, 256, 0, stream>>>(
        (const unsigned short*)wbJ,
        f1, 128, f2, 64, f3, 32, f4, 16, f5, 8,
        5,
        0, 128, 192, 224, 240,
        8,
        x, mu, lsg, scope,
        nullptr,
        out5);

    // 3) levels 6..8: single tree over the 8 level-5 nodes, 128 batch tiles
    circuit_kernel<false><<<128, 256, 0, stream>>>(
        (const unsigned short*)wbJ,
        f6, 4, f7, 2, f8, 1, f8, 0, f8, 0,
        3,
        248, 252, 254, 0, 0,
        1,
        nullptr, nullptr, nullptr, nullptr,
        out5,
        (float*)d_out);
}

// Round 3
// 197.042 us; speedup vs baseline: 2.6128x; 1.7685x over previous
//
#include <hip/hip_runtime.h>
#include <hip/hip_bf16.h>
#include <math.h>

#define LOG2PI_F 0.9189385332046727f

typedef short bf16x8 __attribute__((ext_vector_type(8)));
typedef float f32x4  __attribute__((ext_vector_type(4)));

struct __align__(16) Op { int w; int c0; int c1; int leaf; };

// ---- workspace byte offsets -------------------------------------------------
#define WS_WBJ   0u          // bf16[255*4096]  softmaxed weights, j-major
#define WS_IS    2359296u    // float[256*64]   exp(-log_sigma)
#define WS_CT    2424832u    // float[256*64]   -log_sigma - LOG2PI
#define WS_SCHED 2490368u    // Op[9][31]       post-order schedules
#define WS_OUT5  2621440u    // float[8*2048*64] level-5 node values

__device__ __forceinline__ short bfr(float f) {   // f32 -> bf16 RNE
    unsigned int u = __float_as_uint(f);
    u += 0x7fffu + ((u >> 16) & 1u);
    return (short)(u >> 16);
}

struct F8 { float v[8]; };
__device__ __forceinline__ F8 ld8(const float* p) {
    F8 r;
    float4 a = *(const float4*)p;
    float4 b = *(const float4*)(p + 4);
    r.v[0]=a.x; r.v[1]=a.y; r.v[2]=a.z; r.v[3]=a.w;
    r.v[4]=b.x; r.v[5]=b.y; r.v[6]=b.z; r.v[7]=b.w;
    return r;
}

// ---------------------------------------------------------------------------
// Prep: [0,255) softmax->bf16 j-major; [255,319) leaf-param precompute;
// 319: post-order schedule DFS for the 8 phase-1 subtrees + phase-2 tree.
// ---------------------------------------------------------------------------
__global__ __launch_bounds__(256) void prep_kernel(
    const float* __restrict__ w1, const float* __restrict__ w2,
    const float* __restrict__ w3, const float* __restrict__ w4,
    const float* __restrict__ w5, const float* __restrict__ w6,
    const float* __restrict__ w7, const float* __restrict__ w8,
    const float* __restrict__ ls,
    const int* __restrict__ f1, const int* __restrict__ f2,
    const int* __restrict__ f3, const int* __restrict__ f4,
    const int* __restrict__ f5, const int* __restrict__ f6,
    const int* __restrict__ f7, const int* __restrict__ f8,
    char* __restrict__ ws)
{
    const int bx = blockIdx.x, t = threadIdx.x;
    if (bx < 255) {
        __shared__ float smax[64], ssum[64];
        const int g = bx;
        const float* src;
        if (g < 128)      src = w1 + g * 4096;
        else if (g < 192) src = w2 + (g - 128) * 4096;
        else if (g < 224) src = w3 + (g - 192) * 4096;
        else if (g < 240) src = w4 + (g - 224) * 4096;
        else if (g < 248) src = w5 + (g - 240) * 4096;
        else if (g < 252) src = w6 + (g - 248) * 4096;
        else              src = (g < 254) ? (w7 + (g - 252) * 4096) : w8;
        const int lane = t & 63, wv = t >> 6;
        for (int r = 0; r < 16; ++r) {
            int j = wv * 16 + r;
            float v = src[j * 64 + lane];
            float mx = v;
            for (int d = 1; d < 64; d <<= 1) mx = fmaxf(mx, __shfl_xor(mx, d, 64));
            float e = __expf(v - mx);
            float sm = e;
            for (int d = 1; d < 64; d <<= 1) sm += __shfl_xor(sm, d, 64);
            if (lane == 0) { smax[j] = mx; ssum[j] = sm; }
        }
        __syncthreads();
        unsigned short* dst = (unsigned short*)(ws + WS_WBJ) + g * 4096;
        for (int u = 0; u < 16; ++u) {
            int idx = u * 256 + t;
            int j = idx >> 6;
            dst[idx] = (unsigned short)bfr(__expf(src[idx] - smax[j]) / ssum[j]);
        }
    } else if (bx < 319) {
        const int idx = (bx - 255) * 256 + t;      // 0..16383
        float l = ls[idx];
        ((float*)(ws + WS_IS))[idx] = __expf(-l);
        ((float*)(ws + WS_CT))[idx] = -l - LOG2PI_F;
    } else {
        if (t < 9) {
            Op* out = (Op*)(ws + WS_SCHED) + t * 31;
            const int* lf[6]; int wb[6]; int nl, root;
            if (t < 8) {
                nl = 5; root = t;
                lf[1]=f1; lf[2]=f2; lf[3]=f3; lf[4]=f4; lf[5]=f5;
                wb[1]=0; wb[2]=128; wb[3]=192; wb[4]=224; wb[5]=240;
            } else {
                nl = 3; root = 0;
                lf[1]=f6; lf[2]=f7; lf[3]=f8; lf[4]=f8; lf[5]=f8;
                wb[1]=248; wb[2]=252; wb[3]=254; wb[4]=0; wb[5]=0;
            }
            int sl[8], sf[8], st[8]; int sp = 0, n = 0;
            sl[0] = nl; sf[0] = root; st[0] = 0; sp = 1;
            while (sp > 0) {
                int l = sl[sp-1], f = sf[sp-1];
                if (l == 1) {
                    out[n].w = (wb[1] + f) * 4096;
                    out[n].c0 = lf[1][2*f]; out[n].c1 = lf[1][2*f+1];
                    out[n].leaf = 1; n++; sp--;
                } else if (st[sp-1] == 0) {
                    st[sp-1] = 1;
                    sl[sp] = l-1; sf[sp] = lf[l][2*f]; st[sp] = 0; sp++;
                } else if (st[sp-1] == 1) {
                    st[sp-1] = 2;
                    sl[sp] = l-1; sf[sp] = lf[l][2*f+1]; st[sp] = 0; sp++;
                } else {
                    out[n].w = (wb[l] + f) * 4096;
                    out[n].c0 = 0; out[n].c1 = 0; out[n].leaf = 0; n++; sp--;
                }
            }
        }
    }
}

// ---------------------------------------------------------------------------
// Wave-autonomous MFMA circuit kernel. Block = 1 wave = 64 threads, owning a
// 16-row batch tile and a full subtree DFS. Per node:
//   h (f32, A-layout regs) -> rowmax (in-lane + xor16/32) -> p=exp(h-m) packed
//   to bf16 A-frags -> 8x mfma_f32_16x16x32_bf16 against global-bf16 B-frags
//   (prefetched one op ahead) -> log+m epilogue in C-layout -> LDS stack slot.
// Stack slots: f32 [16][68] (stride 68: C-writes 2-way/free).
// ---------------------------------------------------------------------------
template<bool GAUSS>
__global__ __launch_bounds__(64) void circuit_mfma(
    const unsigned short* __restrict__ wbJ,
    const Op* __restrict__ schedG,
    int nops, int nsub,
    const float* __restrict__ x, const float* __restrict__ mu,
    const float* __restrict__ isg, const float* __restrict__ ctg,
    const int* __restrict__ scope,
    const float* __restrict__ in5,
    float* __restrict__ outg)
{
    __shared__ float slot[5][16 * 68];
    __shared__ Op ops[31];

    const int t  = threadIdx.x;
    const int s  = blockIdx.x % nsub;
    const int b0 = (blockIdx.x / nsub) * 16;

    const Op* sched = schedG + (GAUSS ? s : 8) * 31;
    if (t < nops) *(int4*)&ops[t] = ((const int4*)sched)[t];
    __syncthreads();

    const int m = t & 15;    // A-row (batch) / B-col (j within tile) / D-col
    const int q = t >> 4;    // quad

    // B-frag addressing: frag (jt,kh) = 16B at wbJ[w + ((jt*16+m)*64 + kh*32 + q*8)]
    int4 bf[8];
    {
        const int4* wb4 = (const int4*)(wbJ + ops[0].w);
        #pragma unroll
        for (int jt = 0; jt < 4; ++jt)
            #pragma unroll
            for (int kh = 0; kh < 2; ++kh)
                bf[jt*2+kh] = wb4[(jt*16 + m) * 8 + kh*4 + q];
    }

    int vsp = 0;
    for (int io = 0; io < nops; ++io) {
        const Op op = ops[io];
        int curO, curP;
        if (op.leaf) { curO = vsp; curP = vsp; vsp++; }
        else         { curO = vsp - 2; curP = vsp - 1; vsp--; }

        // prefetch next op's B-frags
        int4 bn[8];
        {
            const int nxt = (io + 1 < nops) ? io + 1 : io;
            const int4* wb4 = (const int4*)(wbJ + ops[nxt].w);
            #pragma unroll
            for (int jt = 0; jt < 4; ++jt)
                #pragma unroll
                for (int kh = 0; kh < 2; ++kh)
                    bn[jt*2+kh] = wb4[(jt*16 + m) * 8 + kh*4 + q];
        }

        // ---- h in A-layout: lane holds h[m][kh*32 + q*8 + i], i=0..7
        float hv[16];
        if (op.leaf) {
            if (GAUSS) {
                const int d0 = op.c0, d1 = op.c1;
                const int v0 = scope[d0], v1 = scope[d1];
                const float xv0 = x[(b0 + m) * 256 + v0];
                const float xv1 = x[(b0 + m) * 256 + v1];
                #pragma unroll
                for (int kh = 0; kh < 2; ++kh) {
                    const int kb = kh * 32 + q * 8;
                    F8 M0 = ld8(mu  + d0*64 + kb), S0 = ld8(isg + d0*64 + kb);
                    F8 C0 = ld8(ctg + d0*64 + kb);
                    F8 M1 = ld8(mu  + d1*64 + kb), S1 = ld8(isg + d1*64 + kb);
                    F8 C1 = ld8(ctg + d1*64 + kb);
                    #pragma unroll
                    for (int i = 0; i < 8; ++i) {
                        float z0 = (xv0 - M0.v[i]) * S0.v[i];
                        float z1 = (xv1 - M1.v[i]) * S1.v[i];
                        hv[kh*8+i] = fmaf(-0.5f * z0, z0, C0.v[i])
                                   + fmaf(-0.5f * z1, z1, C1.v[i]);
                    }
                }
            } else {
                #pragma unroll
                for (int kh = 0; kh < 2; ++kh) {
                    const int kb = kh * 32 + q * 8;
                    F8 A = ld8(in5 + (op.c0 * 2048 + b0 + m) * 64 + kb);
                    F8 B = ld8(in5 + (op.c1 * 2048 + b0 + m) * 64 + kb);
                    #pragma unroll
                    for (int i = 0; i < 8; ++i) hv[kh*8+i] = A.v[i] + B.v[i];
                }
            }
        } else {
            #pragma unroll
            for (int kh = 0; kh < 2; ++kh) {
                const int base = m * 68 + kh * 32 + q * 8;
                F8 A = ld8(&slot[curO][base]);
                F8 B = ld8(&slot[curP][base]);
                #pragma unroll
                for (int i = 0; i < 8; ++i) hv[kh*8+i] = A.v[i] + B.v[i];
            }
        }

        // ---- rowmax over k (in-lane 16, then quads sharing m)
        float hm = hv[0];
        #pragma unroll
        for (int i = 1; i < 16; ++i) hm = fmaxf(hm, hv[i]);
        hm = fmaxf(hm, __shfl_xor(hm, 16, 64));
        hm = fmaxf(hm, __shfl_xor(hm, 32, 64));

        // ---- p = exp(h - m) -> bf16 A-frags
        bf16x8 a0, a1;
        #pragma unroll
        for (int i = 0; i < 8; ++i) {
            a0[i] = bfr(__expf(hv[i]     - hm));
            a1[i] = bfr(__expf(hv[8 + i] - hm));
        }

        // ---- 8x MFMA: D[16x16] per j-tile, K=64 in two steps
        f32x4 acc[4];
        #pragma unroll
        for (int jt = 0; jt < 4; ++jt) {
            f32x4 z = {0.f, 0.f, 0.f, 0.f};
            z = __builtin_amdgcn_mfma_f32_16x16x32_bf16(a0, *(bf16x8*)&bf[jt*2+0], z, 0, 0, 0);
            z = __builtin_amdgcn_mfma_f32_16x16x32_bf16(a1, *(bf16x8*)&bf[jt*2+1], z, 0, 0, 0);
            acc[jt] = z;
        }

        // row-max values for epilogue rows 4q+r (held at lane with m==4q+r)
        float mr[4];
        #pragma unroll
        for (int r = 0; r < 4; ++r) mr[r] = __shfl(hm, q * 4 + r, 64);

        // ---- epilogue: out = log(acc) + m ; C-layout row=4q+r, col=jt*16+m
        if (io == nops - 1) {
            const int ro = GAUSS ? s * 2048 : 0;
            #pragma unroll
            for (int jt = 0; jt < 4; ++jt)
                #pragma unroll
                for (int r = 0; r < 4; ++r)
                    outg[(ro + b0 + q*4 + r) * 64 + jt*16 + m] =
                        __logf(acc[jt][r]) + mr[r];
        } else {
            #pragma unroll
            for (int jt = 0; jt < 4; ++jt)
                #pragma unroll
                for (int r = 0; r < 4; ++r)
                    slot[curO][(q*4 + r) * 68 + jt*16 + m] =
                        __logf(acc[jt][r]) + mr[r];
            __builtin_amdgcn_wave_barrier();
            __builtin_amdgcn_s_waitcnt(0xC07F);   // lgkmcnt(0): writes visible
            __builtin_amdgcn_wave_barrier();
        }

        #pragma unroll
        for (int u = 0; u < 8; ++u) bf[u] = bn[u];
    }
}

// ---------------------------------------------------------------------------
// d_in order: 0:x 1:mu 2:log_sigma 3:in_scope_idx, then fold_idx{l}, w{l}
// ---------------------------------------------------------------------------
extern "C" void kernel_launch(void* const* d_in, const int* in_sizes, int n_in,
                              void* d_out, int out_size, void* d_ws, size_t ws_size,
                              hipStream_t stream) {
    const float* x     = (const float*)d_in[0];
    const float* mu    = (const float*)d_in[1];
    const float* lsg   = (const float*)d_in[2];
    const int*   scope = (const int*)d_in[3];
    const int*   f1 = (const int*)d_in[4];   const float* w1 = (const float*)d_in[5];
    const int*   f2 = (const int*)d_in[6];   const float* w2 = (const float*)d_in[7];
    const int*   f3 = (const int*)d_in[8];   const float* w3 = (const float*)d_in[9];
    const int*   f4 = (const int*)d_in[10];  const float* w4 = (const float*)d_in[11];
    const int*   f5 = (const int*)d_in[12];  const float* w5 = (const float*)d_in[13];
    const int*   f6 = (const int*)d_in[14];  const float* w6 = (const float*)d_in[15];
    const int*   f7 = (const int*)d_in[16];  const float* w7 = (const float*)d_in[17];
    const int*   f8 = (const int*)d_in[18];  const float* w8 = (const float*)d_in[19];

    char* ws = (char*)d_ws;
    const unsigned short* wbJ = (const unsigned short*)(ws + WS_WBJ);
    const float* isg  = (const float*)(ws + WS_IS);
    const float* ctg  = (const float*)(ws + WS_CT);
    const Op*    sch  = (const Op*)(ws + WS_SCHED);
    float*       out5 = (float*)(ws + WS_OUT5);

    prep_kernel<<<320, 256, 0, stream>>>(w1, w2, w3, w4, w5, w6, w7, w8,
                                         lsg, f1, f2, f3, f4, f5, f6, f7, f8, ws);

    // levels 1..5: 8 subtrees x 128 tiles of 16 rows, one wave per block
    circuit_mfma<true><<<1024, 64, 0, stream>>>(
        wbJ, sch, 31, 8,
        x, mu, isg, ctg, scope,
        nullptr, out5);

    // levels 6..8: 128 tiles
    circuit_mfma<false><<<128, 64, 0, stream>>>(
        wbJ, sch, 7, 1,
        nullptr, nullptr, nullptr, nullptr, nullptr,
        out5, (float*)d_out);
}

// Round 4
// 164.761 us; speedup vs baseline: 3.1247x; 1.1959x over previous
//
#include <hip/hip_runtime.h>
#include <math.h>

#define LOG2PI_F  0.9189385332046727f
#define INV_LN2_F 1.4426950408889634f
#define LN2_F     0.6931471805599453f

typedef short bf16x8 __attribute__((ext_vector_type(8)));
typedef float f32x4  __attribute__((ext_vector_type(4)));

struct __align__(16) Op { int w; int c0; int c1; int leaf; };

// ---- workspace byte offsets -------------------------------------------------
#define WS_WBJ   0u          // bf16[255*4096] softmaxed weights, j-major, linear
#define WS_A     2097152u    // float[256*64]  leaf coeff A (log2 domain)
#define WS_B     2162688u    // float[256*64]  leaf coeff B
#define WS_C     2228224u    // float[256*64]  leaf coeff C
#define WS_XT    2293760u    // float[256*2048] x gathered+transposed: xT[d][b]
#define WS_SCHED 4390912u    // Op[255] schedules: K14 16x15 @0, K56 4x3 @240, K78 3 @252
#define WS_L4    4395008u    // float[16*2048*64] level-4 values (log2)
#define WS_L6    12783616u   // float[4*2048*64]  level-6 values (log2)
// total ~14.2 MB

__device__ __forceinline__ short bfr(float f) {   // f32 -> bf16 RNE
    unsigned int u = __float_as_uint(f);
    u += 0x7fffu + ((u >> 16) & 1u);
    return (short)(u >> 16);
}

struct F8 { float v[8]; };
__device__ __forceinline__ F8 ld8(const float* p) {
    F8 r;
    float4 a = *(const float4*)p;
    float4 b = *(const float4*)(p + 4);
    r.v[0]=a.x; r.v[1]=a.y; r.v[2]=a.z; r.v[3]=a.w;
    r.v[4]=b.x; r.v[5]=b.y; r.v[6]=b.z; r.v[7]=b.w;
    return r;
}

// ---------------------------------------------------------------------------
// Prep: [0,255) softmax->bf16 j-major; [255,319) leaf quadratic coeffs;
// [319,575) x transpose/gather; 575: post-order schedules.
// ---------------------------------------------------------------------------
__global__ __launch_bounds__(256) void prep_kernel(
    const float* __restrict__ w1, const float* __restrict__ w2,
    const float* __restrict__ w3, const float* __restrict__ w4,
    const float* __restrict__ w5, const float* __restrict__ w6,
    const float* __restrict__ w7, const float* __restrict__ w8,
    const float* __restrict__ mu, const float* __restrict__ ls,
    const float* __restrict__ x,  const int* __restrict__ scope,
    const int* __restrict__ f1, const int* __restrict__ f2,
    const int* __restrict__ f3, const int* __restrict__ f4,
    const int* __restrict__ f5, const int* __restrict__ f6,
    const int* __restrict__ f7, const int* __restrict__ f8,
    char* __restrict__ ws)
{
    const int bx = blockIdx.x, t = threadIdx.x;
    if (bx < 255) {
        __shared__ float smax[64], ssum[64];
        const int g = bx;
        const float* src;
        if (g < 128)      src = w1 + g * 4096;
        else if (g < 192) src = w2 + (g - 128) * 4096;
        else if (g < 224) src = w3 + (g - 192) * 4096;
        else if (g < 240) src = w4 + (g - 224) * 4096;
        else if (g < 248) src = w5 + (g - 240) * 4096;
        else if (g < 252) src = w6 + (g - 248) * 4096;
        else              src = (g < 254) ? (w7 + (g - 252) * 4096) : w8;
        const int lane = t & 63, wv = t >> 6;
        for (int r = 0; r < 16; ++r) {
            int j = wv * 16 + r;
            float v = src[j * 64 + lane];
            float mx = v;
            for (int d = 1; d < 64; d <<= 1) mx = fmaxf(mx, __shfl_xor(mx, d, 64));
            float e = __expf(v - mx);
            float sm = e;
            for (int d = 1; d < 64; d <<= 1) sm += __shfl_xor(sm, d, 64);
            if (lane == 0) { smax[j] = mx; ssum[j] = sm; }
        }
        __syncthreads();
        unsigned short* dst = (unsigned short*)(ws + WS_WBJ) + g * 4096;
        for (int u = 0; u < 16; ++u) {
            int idx = u * 256 + t;
            int j = idx >> 6;
            dst[idx] = (unsigned short)bfr(__expf(src[idx] - smax[j]) / ssum[j]);
        }
    } else if (bx < 319) {
        // h_leaf(d,k)(x) = A x^2 + B x + C   (already scaled to log2 domain)
        const int idx = (bx - 255) * 256 + t;      // 0..16383
        float m = mu[idx], l = ls[idx];
        float is2 = __expf(-2.0f * l);
        ((float*)(ws + WS_A))[idx] = -0.5f * is2 * INV_LN2_F;
        ((float*)(ws + WS_B))[idx] = m * is2 * INV_LN2_F;
        ((float*)(ws + WS_C))[idx] = (-0.5f * m * m * is2 - l - LOG2PI_F) * INV_LN2_F;
    } else if (bx < 575) {
        const int bb = bx - 319;                    // 0..255, batch range [8bb, 8bb+8)
        const int sd = scope[t];                    // lane t = leaf slot d
        float* xT = (float*)(ws + WS_XT);
        #pragma unroll
        for (int i = 0; i < 8; ++i) {
            int b = bb * 8 + i;
            xT[t * 2048 + b] = x[b * 256 + sd];
        }
    } else {
        if (t < 21) {
            Op* base = (Op*)(ws + WS_SCHED);
            Op* out; const int* lf[5]; int wb[5]; int nl, root;
            if (t < 16) {
                nl = 4; root = t; out = base + t * 15;
                lf[1]=f1; lf[2]=f2; lf[3]=f3; lf[4]=f4;
                wb[1]=0; wb[2]=128; wb[3]=192; wb[4]=224;
            } else if (t < 20) {
                nl = 2; root = t - 16; out = base + 240 + (t - 16) * 3;
                lf[1]=f5; lf[2]=f6; wb[1]=240; wb[2]=248;
            } else {
                nl = 2; root = 0; out = base + 252;
                lf[1]=f7; lf[2]=f8; wb[1]=252; wb[2]=254;
            }
            int sl[8], sf[8], st[8]; int sp = 0, n = 0;
            sl[0] = nl; sf[0] = root; st[0] = 0; sp = 1;
            while (sp > 0) {
                int l = sl[sp-1], f = sf[sp-1];
                if (l == 1) {
                    out[n].w = (wb[1] + f) * 4096;
                    out[n].c0 = lf[1][2*f]; out[n].c1 = lf[1][2*f+1];
                    out[n].leaf = 1; n++; sp--;
                } else if (st[sp-1] == 0) {
                    st[sp-1] = 1;
                    sl[sp] = l-1; sf[sp] = lf[l][2*f]; st[sp] = 0; sp++;
                } else if (st[sp-1] == 1) {
                    st[sp-1] = 2;
                    sl[sp] = l-1; sf[sp] = lf[l][2*f+1]; st[sp] = 0; sp++;
                } else {
                    out[n].w = (wb[l] + f) * 4096;
                    out[n].c0 = 0; out[n].c1 = 0; out[n].leaf = 0; n++; sp--;
                }
            }
        }
    }
}

// ---------------------------------------------------------------------------
// Wave-autonomous MFMA circuit kernel, log2-domain values throughout.
// Block = 1 wave = 64 threads, 16-row batch tile, post-order walk of `nops`
// ops. GAUSS: leaf ops evaluate Gaussians via (A,B,C, xT); else leaf ops sum
// two child rows from in5 (node-id indexed). Root epilogue scales by outScale
// (1.0 for intermediate levels, ln2 for the final output back to natural log).
// ---------------------------------------------------------------------------
template<bool GAUSS>
__global__ __launch_bounds__(64) void circuit_mfma(
    const unsigned short* __restrict__ wbJ,
    const Op* __restrict__ schedG, int nops, int nsub,
    const float* __restrict__ xT, const float* __restrict__ Ag,
    const float* __restrict__ Bg, const float* __restrict__ Cg,
    const float* __restrict__ in5,
    float* __restrict__ outg, float outScale)
{
    __shared__ float slot[4][16 * 68];
    __shared__ Op ops[15];

    const int t  = threadIdx.x;
    const int s  = blockIdx.x % nsub;
    const int b0 = (blockIdx.x / nsub) * 16;

    const Op* sched = schedG + s * nops;
    if (t < nops) *(int4*)&ops[t] = ((const int4*)sched)[t];
    __syncthreads();

    const int m = t & 15;    // A-row (batch) / B-col (j within tile) / D-col
    const int q = t >> 4;    // quad

    // B-frag (jt,kh): 16B at wbJ[w + ((jt*16+m)*64 + kh*32 + q*8)]
    int4 bf[8];
    {
        const int4* wb4 = (const int4*)(wbJ + ops[0].w);
        #pragma unroll
        for (int jt = 0; jt < 4; ++jt)
            #pragma unroll
            for (int kh = 0; kh < 2; ++kh)
                bf[jt*2+kh] = wb4[(jt*16 + m) * 8 + kh*4 + q];
    }

    int vsp = 0;
    for (int io = 0; io < nops; ++io) {
        const Op op = ops[io];
        int curO, curP;
        if (op.leaf) { curO = vsp; curP = vsp; vsp++; }
        else         { curO = vsp - 2; curP = vsp - 1; vsp--; }

        // prefetch next op's B-frags
        int4 bn[8];
        {
            const int nxt = (io + 1 < nops) ? io + 1 : io;
            const int4* wb4 = (const int4*)(wbJ + ops[nxt].w);
            #pragma unroll
            for (int jt = 0; jt < 4; ++jt)
                #pragma unroll
                for (int kh = 0; kh < 2; ++kh)
                    bn[jt*2+kh] = wb4[(jt*16 + m) * 8 + kh*4 + q];
        }

        // ---- h (log2 domain), A-layout: lane holds h[m][kh*32 + q*8 + i]
        float hv[16];
        if (op.leaf) {
            if (GAUSS) {
                const int d0 = op.c0, d1 = op.c1;
                const float xv0 = xT[d0 * 2048 + b0 + m];
                const float xv1 = xT[d1 * 2048 + b0 + m];
                const float x0s = xv0 * xv0, x1s = xv1 * xv1;
                #pragma unroll
                for (int kh = 0; kh < 2; ++kh) {
                    const int kb = kh * 32 + q * 8;
                    F8 A0 = ld8(Ag + d0*64 + kb), B0 = ld8(Bg + d0*64 + kb);
                    F8 C0 = ld8(Cg + d0*64 + kb);
                    F8 A1 = ld8(Ag + d1*64 + kb), B1 = ld8(Bg + d1*64 + kb);
                    F8 C1 = ld8(Cg + d1*64 + kb);
                    #pragma unroll
                    for (int i = 0; i < 8; ++i) {
                        float t0 = fmaf(A0.v[i], x0s, C0.v[i]);
                        t0 = fmaf(B0.v[i], xv0, t0);
                        float t1 = fmaf(A1.v[i], x1s, C1.v[i]);
                        t1 = fmaf(B1.v[i], xv1, t1);
                        hv[kh*8+i] = t0 + t1;
                    }
                }
            } else {
                #pragma unroll
                for (int kh = 0; kh < 2; ++kh) {
                    const int kb = kh * 32 + q * 8;
                    F8 A = ld8(in5 + (op.c0 * 2048 + b0 + m) * 64 + kb);
                    F8 B = ld8(in5 + (op.c1 * 2048 + b0 + m) * 64 + kb);
                    #pragma unroll
                    for (int i = 0; i < 8; ++i) hv[kh*8+i] = A.v[i] + B.v[i];
                }
            }
        } else {
            #pragma unroll
            for (int kh = 0; kh < 2; ++kh) {
                const int base = m * 68 + kh * 32 + q * 8;
                F8 A = ld8(&slot[curO][base]);
                F8 B = ld8(&slot[curP][base]);
                #pragma unroll
                for (int i = 0; i < 8; ++i) hv[kh*8+i] = A.v[i] + B.v[i];
            }
        }

        // ---- rowmax over k (tree in-lane, then quads sharing m)
        float m01 = fmaxf(hv[0], hv[1]),  m23 = fmaxf(hv[2], hv[3]);
        float m45 = fmaxf(hv[4], hv[5]),  m67 = fmaxf(hv[6], hv[7]);
        float m89 = fmaxf(hv[8], hv[9]),  mab = fmaxf(hv[10], hv[11]);
        float mcd = fmaxf(hv[12], hv[13]), mef = fmaxf(hv[14], hv[15]);
        float hm = fmaxf(fmaxf(fmaxf(m01, m23), fmaxf(m45, m67)),
                         fmaxf(fmaxf(m89, mab), fmaxf(mcd, mef)));
        hm = fmaxf(hm, __shfl_xor(hm, 16, 64));
        hm = fmaxf(hm, __shfl_xor(hm, 32, 64));

        // ---- p = exp2(h - m) -> bf16 A-frags (pack: v_perm truncation)
        float e[16];
        #pragma unroll
        for (int i = 0; i < 16; ++i) e[i] = __builtin_amdgcn_exp2f(hv[i] - hm);
        int4 p0, p1;
        p0.x = __builtin_amdgcn_perm(__float_as_uint(e[1]),  __float_as_uint(e[0]),  0x07060302u);
        p0.y = __builtin_amdgcn_perm(__float_as_uint(e[3]),  __float_as_uint(e[2]),  0x07060302u);
        p0.z = __builtin_amdgcn_perm(__float_as_uint(e[5]),  __float_as_uint(e[4]),  0x07060302u);
        p0.w = __builtin_amdgcn_perm(__float_as_uint(e[7]),  __float_as_uint(e[6]),  0x07060302u);
        p1.x = __builtin_amdgcn_perm(__float_as_uint(e[9]),  __float_as_uint(e[8]),  0x07060302u);
        p1.y = __builtin_amdgcn_perm(__float_as_uint(e[11]), __float_as_uint(e[10]), 0x07060302u);
        p1.z = __builtin_amdgcn_perm(__float_as_uint(e[13]), __float_as_uint(e[12]), 0x07060302u);
        p1.w = __builtin_amdgcn_perm(__float_as_uint(e[15]), __float_as_uint(e[14]), 0x07060302u);
        bf16x8 a0 = *(bf16x8*)&p0;
        bf16x8 a1 = *(bf16x8*)&p1;

        // ---- 8x MFMA: D[16x16] per j-tile, K=64 in two steps
        f32x4 acc[4];
        #pragma unroll
        for (int jt = 0; jt < 4; ++jt) {
            f32x4 z = {0.f, 0.f, 0.f, 0.f};
            z = __builtin_amdgcn_mfma_f32_16x16x32_bf16(a0, *(bf16x8*)&bf[jt*2+0], z, 0, 0, 0);
            z = __builtin_amdgcn_mfma_f32_16x16x32_bf16(a1, *(bf16x8*)&bf[jt*2+1], z, 0, 0, 0);
            acc[jt] = z;
        }

        // row-max values for epilogue rows 4q+r
        float mr[4];
        #pragma unroll
        for (int r = 0; r < 4; ++r) mr[r] = __shfl(hm, q * 4 + r, 64);

        // ---- epilogue: out = log2(acc) + m ; C-layout row=4q+r, col=jt*16+m
        if (io == nops - 1) {
            #pragma unroll
            for (int jt = 0; jt < 4; ++jt)
                #pragma unroll
                for (int r = 0; r < 4; ++r)
                    outg[(s * 2048 + b0 + q*4 + r) * 64 + jt*16 + m] =
                        (__builtin_amdgcn_logf(acc[jt][r]) + mr[r]) * outScale;
        } else {
            #pragma unroll
            for (int jt = 0; jt < 4; ++jt)
                #pragma unroll
                for (int r = 0; r < 4; ++r)
                    slot[curO][(q*4 + r) * 68 + jt*16 + m] =
                        __builtin_amdgcn_logf(acc[jt][r]) + mr[r];
            __builtin_amdgcn_wave_barrier();
            __builtin_amdgcn_s_waitcnt(0xC07F);   // lgkmcnt(0)
            __builtin_amdgcn_wave_barrier();
        }

        #pragma unroll
        for (int u = 0; u < 8; ++u) bf[u] = bn[u];
    }
}

// ---------------------------------------------------------------------------
// d_in order: 0:x 1:mu 2:log_sigma 3:in_scope_idx, then fold_idx{l}, w{l}
// ---------------------------------------------------------------------------
extern "C" void kernel_launch(void* const* d_in, const int* in_sizes, int n_in,
                              void* d_out, int out_size, void* d_ws, size_t ws_size,
                              hipStream_t stream) {
    const float* x     = (const float*)d_in[0];
    const float* mu    = (const float*)d_in[1];
    const float* lsg   = (const float*)d_in[2];
    const int*   scope = (const int*)d_in[3];
    const int*   f1 = (const int*)d_in[4];   const float* w1 = (const float*)d_in[5];
    const int*   f2 = (const int*)d_in[6];   const float* w2 = (const float*)d_in[7];
    const int*   f3 = (const int*)d_in[8];   const float* w3 = (const float*)d_in[9];
    const int*   f4 = (const int*)d_in[10];  const float* w4 = (const float*)d_in[11];
    const int*   f5 = (const int*)d_in[12];  const float* w5 = (const float*)d_in[13];
    const int*   f6 = (const int*)d_in[14];  const float* w6 = (const float*)d_in[15];
    const int*   f7 = (const int*)d_in[16];  const float* w7 = (const float*)d_in[17];
    const int*   f8 = (const int*)d_in[18];  const float* w8 = (const float*)d_in[19];

    char* ws = (char*)d_ws;
    const unsigned short* wbJ = (const unsigned short*)(ws + WS_WBJ);
    const float* Ag  = (const float*)(ws + WS_A);
    const float* Bg  = (const float*)(ws + WS_B);
    const float* Cg  = (const float*)(ws + WS_C);
    const float* xT  = (const float*)(ws + WS_XT);
    const Op*    sch = (const Op*)(ws + WS_SCHED);
    float*       L4  = (float*)(ws + WS_L4);
    float*       L6  = (float*)(ws + WS_L6);

    prep_kernel<<<576, 256, 0, stream>>>(w1, w2, w3, w4, w5, w6, w7, w8,
                                         mu, lsg, x, scope,
                                         f1, f2, f3, f4, f5, f6, f7, f8, ws);

    // levels 1..4: 16 roots x 128 tiles = 2048 wave-jobs, 15 ops each
    circuit_mfma<true><<<2048, 64, 0, stream>>>(
        wbJ, sch, 15, 16,
        xT, Ag, Bg, Cg,
        nullptr, L4, 1.0f);

    // levels 5..6: 4 roots x 128 tiles = 512 jobs, 3 ops each
    circuit_mfma<false><<<512, 64, 0, stream>>>(
        wbJ, sch + 240, 3, 4,
        nullptr, nullptr, nullptr, nullptr,
        L4, L6, 1.0f);

    // levels 7..8: 128 jobs, 3 ops, final output scaled back to natural log
    circuit_mfma<false><<<128, 64, 0, stream>>>(
        wbJ, sch + 252, 3, 1,
        nullptr, nullptr, nullptr, nullptr,
        L6, (float*)d_out, LN2_F);
}